// Round 13
// baseline (126.467 us; speedup 1.0000x reference)
//
#include <hip/hip_runtime.h>
#include <stdint.h>

#define TT 16
#define BB 16
#define CC 256
#define HS 31
#define HT 15
#define OUTW 17
#define NCH 15                      // channels per block; 15*17 = 255/256 lanes active
#define NCHAN (BB*TT*CC)            // 65536
#define CORR_ELEMS ((size_t)NCHAN*OUTW*OUTW)
#define SROW 20                     // dwords per s row (16 data + 4 pad; pad holds w)
#define SCH  620                    // dwords per channel; LDS = 15*620*4 = 37200 B -> 4 blocks/CU

typedef _Float16 h2_t  __attribute__((ext_vector_type(2)));
typedef unsigned u32x4 __attribute__((ext_vector_type(4)));

__device__ __forceinline__ unsigned packh2(float a, float b) {
    return __builtin_bit_cast(unsigned, __builtin_amdgcn_cvt_pkrtz(a, b));
}
__device__ __forceinline__ float fdot2f(unsigned a, unsigned b, float c) {
    return __builtin_amdgcn_fdot2(__builtin_bit_cast(h2_t, a),
                                  __builtin_bit_cast(h2_t, b), c, false);
}

// logical channel ch = (b*T + t)*C + c  ->  s_f index (t*B + b)*C + c
__device__ __forceinline__ int s_index(int ch) {
    int bt = ch >> 8, c = ch & 255;
    int b = bt >> 4, t = bt & 15;
    return (t * BB + b) * CC + c;
}

__global__ __launch_bounds__(256, 1)
void corr_kernel(const float* __restrict__ s_f, const float* __restrict__ t_f,
                 const int* __restrict__ pos,
                 float* __restrict__ corr, float* __restrict__ masks)
{
    __shared__ unsigned lds[NCH * SCH];   // 37200 B

    const int tid = threadIdx.x;
    const int ch_base = blockIdx.x * NCH;

    // ---- stage s: issue ALL loads first (fire-and-forget), then pack+write ----
    {
        const int jcol = tid & 15;
        const int r0   = tid >> 4;          // 0..15
        const int x0   = 2 * jcol;
        const bool hasb  = (jcol < 15);     // pair (30,31): x=31 doesn't exist
        const int  r1    = r0 + 16;
        const bool hasr1 = (r1 <= 30);
        const int xa = hasb ? x0 : x0 - 1;  // shifted 8B load stays in-bounds at tail

        float2 La[NCH], Lb[NCH];
#pragma unroll
        for (int j = 0; j < NCH; ++j) {
            int ch = ch_base + j; if (ch >= NCHAN) ch = NCHAN - 1;
            const float* src = s_f + (size_t)s_index(ch) * (HS * HS);
            La[j] = *(const float2*)(src + r0 * HS + xa);
            Lb[j] = hasr1 ? *(const float2*)(src + r1 * HS + xa)
                          : make_float2(0.f, 0.f);
        }
#pragma unroll
        for (int j = 0; j < NCH; ++j) {
            float a0 = hasb ? La[j].x : La[j].y;
            float b0 = hasb ? La[j].y : 0.0f;
            lds[j * SCH + r0 * SROW + jcol] = packh2(a0, b0);
            if (hasr1) {
                float a1 = hasb ? Lb[j].x : Lb[j].y;
                float b1 = hasb ? Lb[j].y : 0.0f;
                lds[j * SCH + r1 * SROW + jcol] = packh2(a1, b1);
            }
        }
    }

    // ---- stage w into the row pads: w row ky (8 pair-dwords) at 40ky+16..19, 40ky+36..39 ----
    {
        float2 Lw[8];
        int    off[8];
#pragma unroll
        for (int it = 0; it < 8; ++it) {
            int idx = tid + 256 * it;               // < 1800 = NCH*HT*8 (tail masked)
            bool ok = idx < NCH * HT * 8;
            int i2  = ok ? idx : 0;
            int j   = i2 / (HT * 8);
            int e   = i2 - j * (HT * 8);
            int ky  = e >> 3, p = e & 7;
            int ch  = ch_base + j; if (ch >= NCHAN) ch = NCHAN - 1;
            int bt = ch >> 8, c = ch & 255, b = bt >> 4;
            const float* wsrc = t_f + (size_t)(b * CC + c) * (HT * HT) + ky * HT;
            int xw = (p < 7) ? 2 * p : 13;          // p==7: load (13,14), keep .y
            Lw[it] = *(const float2*)(wsrc + xw);
            off[it] = ok ? (j * SCH + 40 * ky + 16 + ((p & 4) ? 20 + (p & 3) : (p & 3)))
                         : -1;
            if (p == 7) { Lw[it].x = Lw[it].y; Lw[it].y = 0.0f; }
        }
#pragma unroll
        for (int it = 0; it < 8; ++it)
            if (off[it] >= 0) lds[off[it]] = packh2(Lw[it].x, Lw[it].y);
    }

    __syncthreads();

    // ---- compute: thread = (c_sub, oy) owns one 17-wide output row ----
    const int c_sub = tid / OUTW;
    const int oy    = tid - c_sub * OUTW;
    if (c_sub >= NCH) return;
    const int ch = ch_base + c_sub;
    if (ch >= NCHAN) return;

    const unsigned* chb = lds + c_sub * SCH;

    float acc[OUTW];
#pragma unroll
    for (int m = 0; m < OUTW; ++m) acc[m] = 0.0f;

    // LDS byte addresses (generic-pointer low 32 bits = LDS offset)
    unsigned sA = (unsigned)(uintptr_t)(const void*)chb + (unsigned)(oy * (SROW * 4));
    unsigned wA = (unsigned)(uintptr_t)(const void*)chb;

    u32x4 A0, A1, A2, A3, AW0, AW1;
    u32x4 B0, B1, B2, B3, BW0, BW1;

// 6 opaque ds_read_b128: 4 s-row dwords chunks + 2 w chunks. Offsets literal.
#define LDS6(S0,S1,S2,S3,W0,W1, O0,O1,O2,O3, WO0,WO1)                      \
    asm volatile(                                                          \
        "ds_read_b128 %0, %6 offset:" O0 "\n\t"                            \
        "ds_read_b128 %1, %6 offset:" O1 "\n\t"                            \
        "ds_read_b128 %2, %6 offset:" O2 "\n\t"                            \
        "ds_read_b128 %3, %6 offset:" O3 "\n\t"                            \
        "ds_read_b128 %4, %7 offset:" WO0 "\n\t"                           \
        "ds_read_b128 %5, %7 offset:" WO1                                  \
        : "=v"(S0), "=v"(S1), "=v"(S2), "=v"(S3), "=v"(W0), "=v"(W1)       \
        : "v"(sA), "v"(wA))

#define WAITL() do { asm volatile("s_waitcnt lgkmcnt(0)");                 \
                     __builtin_amdgcn_sched_barrier(0); } while (0)

#define COMPUTE(S0,S1,S2,S3,W0,W1) do {                                    \
        unsigned sp[16] = {S0[0],S0[1],S0[2],S0[3], S1[0],S1[1],S1[2],S1[3], \
                           S2[0],S2[1],S2[2],S2[3], S3[0],S3[1],S3[2],S3[3]}; \
        unsigned wp[8]  = {W0[0],W0[1],W0[2],W0[3], W1[0],W1[1],W1[2],W1[3]}; \
        unsigned wo_[8];                                                   \
        wo_[0] = wp[0] << 16;                                              \
        _Pragma("unroll")                                                  \
        for (int r = 1; r < 8; ++r)                                        \
            wo_[r] = __builtin_amdgcn_alignbit(wp[r], wp[r - 1], 16);      \
        _Pragma("unroll")                                                  \
        for (int e = 0; e < 9; ++e)                                        \
            _Pragma("unroll")                                              \
            for (int jj = 0; jj < 8; ++jj)                                 \
                acc[2 * e] = fdot2f(sp[e + jj], wp[jj], acc[2 * e]);       \
        _Pragma("unroll")                                                  \
        for (int o = 0; o < 8; ++o)                                        \
            _Pragma("unroll")                                              \
            for (int r = 0; r < 8; ++r)                                    \
                acc[2 * o + 1] = fdot2f(sp[o + r], wo_[r], acc[2 * o + 1]);\
    } while (0)

    // prologue: ky = 0 (s row at +0; w row 0 at +64/+144)
    LDS6(A0,A1,A2,A3,AW0,AW1, "0","16","32","48", "64","144");
    WAITL();
#pragma unroll 1
    for (int kk = 0; kk < 7; ++kk) {
        // ky = 2kk+1: s +80; w 160*(2kk+1)+64 -> +224/+304 rel. wA(kk)
        LDS6(B0,B1,B2,B3,BW0,BW1, "80","96","112","128", "224","304");
        COMPUTE(A0,A1,A2,A3,AW0,AW1);
        WAITL();
        // ky = 2kk+2: s +160; w +384/+464
        LDS6(A0,A1,A2,A3,AW0,AW1, "160","176","192","208", "384","464");
        COMPUTE(B0,B1,B2,B3,BW0,BW1);
        WAITL();
        sA += 160; wA += 320;
    }
    COMPUTE(A0,A1,A2,A3,AW0,AW1);   // ky = 14

#undef LDS6
#undef WAITL
#undef COMPUTE

    // ---- epilogue: corr row + fused masks gather ----
    float* outp = corr + (size_t)ch * (OUTW * OUTW) + (size_t)oy * OUTW;
#pragma unroll
    for (int m = 0; m < OUTW; ++m) outp[m] = acc[m];

    const int bt = ch >> 8;
    const int p0 = pos[2 * bt];
    const int p1 = pos[2 * bt + 1];
    if (oy == p0) {
        float v = acc[0];
#pragma unroll
        for (int m = 1; m < OUTW; ++m) v = (p1 == m) ? acc[m] : v;
        masks[ch] = v;
    }
}

extern "C" void kernel_launch(void* const* d_in, const int* in_sizes, int n_in,
                              void* d_out, int out_size, void* d_ws, size_t ws_size,
                              hipStream_t stream)
{
    const float* s_f = (const float*)d_in[0];
    const float* t_f = (const float*)d_in[1];
    const int*   pos = (const int*)d_in[2];
    float* corr  = (float*)d_out;
    float* masks = corr + CORR_ELEMS;

    int nblocks = (NCHAN + NCH - 1) / NCH;   // 4370
    corr_kernel<<<nblocks, 256, 0, stream>>>(s_f, t_f, pos, corr, masks);
}